// Round 11
// baseline (359.646 us; speedup 1.0000x reference)
//
#include <hip/hip_runtime.h>

#define ROWSB 32     // rows per block; 4 waves x 8 rows (wave == agent group)
#define HIDN 256
#define TT 8
#define EPSI 1e-6f
#define HAS 260      // ha/vbuf row stride (floats)
#define SVS 260      // sorted-vocab row stride in ws (257 used + 3 INF pad)
#define TBSTR 40
#define NCELL 512
#define WS_LUT_F   (32*SVS)                 // ushort lut[32][512] == 8192 floats
#define WS_DINFO_F (32*SVS + 8192)          // float2 dinfo[32] (base, scale)
#define WS_WMV_F   (32*SVS + 8192 + 64)     // interleaved [j][d][(mu,var)] = 16384 floats

typedef float v2f __attribute__((ext_vector_type(2)));

__device__ __forceinline__ void ld4(float* d, const float* p) {
  float4 v = *(const float4*)p;
  d[0] = v.x; d[1] = v.y; d[2] = v.z; d[3] = v.w;
}
__device__ __forceinline__ void ld2(float* d, const float* p) {
  float2 v = *(const float2*)p;
  d[0] = v.x; d[1] = v.y;
}
// Order own-wave LDS write->read without draining the global-load (vmcnt) queue.
__device__ __forceinline__ void lds_fence() {
  asm volatile("s_waitcnt lgkmcnt(0)" ::: "memory");
}
// Packed GEMV step: 8 FMAs as 4 v_pk_fma_f32. wv = (mu[d0],var[d0],mu[d1],var[d1]).
// Accumulators: A00=(mu0[0],lv0[0]) A01=(mu0[1],lv0[1]) A10/A11 = row1.
// Per-accumulator FMA order identical to the scalar version -> bit-exact.
__device__ __forceinline__ void fma8p(float4 wv, float h0, float h1,
                                      v2f& A00, v2f& A01, v2f& A10, v2f& A11) {
  v2f wl = {wv.x, wv.y}, wh = {wv.z, wv.w};
  v2f h0v = {h0, h0},   h1v = {h1, h1};
  A00 += h0v*wl; A01 += h0v*wh;
  A10 += h1v*wl; A11 += h1v*wh;
}

// ---- DPP cross-lane reductions (pure VALU, zero lgkm) ----
#define DPP_ADD(x, ctrl) \
  (x) += __int_as_float(__builtin_amdgcn_update_dpp(0, __float_as_int(x), (ctrl), 0xf, 0xf, true))
__device__ __forceinline__ float wave_sum64(float x) {
  DPP_ADD(x, 0x111);  // row_shr:1
  DPP_ADD(x, 0x112);  // row_shr:2
  DPP_ADD(x, 0x114);  // row_shr:4
  DPP_ADD(x, 0x118);  // row_shr:8
  DPP_ADD(x, 0x142);  // row_bcast:15
  DPP_ADD(x, 0x143);  // row_bcast:31 -> lane63 = sum(0..63)
  return __int_as_float(__builtin_amdgcn_readlane(__float_as_int(x), 63));
}
// 8-lane group sum: valid ONLY at top lane of each group (c4 & 7) == 7.
__device__ __forceinline__ float grp8_sum(float x) {
  DPP_ADD(x, 0x111);
  DPP_ADD(x, 0x112);
  DPP_ADD(x, 0x114);
  return x;
}

// ---------- pre-pass: per-dim bitonic sort + 512-cell LUT + (mu,var) weight interleave ----------
__global__ __launch_bounds__(256)
void sort_vocab(const float* __restrict__ vocab,
                const float* __restrict__ Wmu, const float* __restrict__ Wvar,
                float* __restrict__ ws) {
  __shared__ float arr[512];
  const int d = blockIdx.x;
  const int t = threadIdx.x;
  ws[WS_WMV_F + ((size_t)t*32 + d)*2 + 0] = Wmu[(size_t)t*32 + d];
  ws[WS_WMV_F + ((size_t)t*32 + d)*2 + 1] = Wvar[(size_t)t*32 + d];
  arr[t] = (t < 257) ? vocab[t*32 + d] : 3.0e38f;
  arr[t+256] = (t == 0) ? vocab[256*32 + d] : 3.0e38f;
  __syncthreads();
  for (int k = 2; k <= 512; k <<= 1) {
    for (int j = k >> 1; j > 0; j >>= 1) {
      #pragma unroll
      for (int h = 0; h < 2; ++h) {
        int i = t + h*256;
        int ixj = i ^ j;
        if (ixj > i) {
          float a = arr[i], b = arr[ixj];
          bool up = ((i & k) == 0);
          if ((a > b) == up) { arr[i] = b; arr[ixj] = a; }
        }
      }
      __syncthreads();
    }
  }
  #pragma unroll
  for (int h = 0; h < 2; ++h) {
    int i = t + h*256;
    if (i < SVS) ws[d*SVS + i] = (i < 257) ? arr[i] : 3.0e38f;
  }
  float base = arr[0];
  float maxv = arr[256];
  float scale = (float)NCELL / fmaxf(maxv - base, 1e-30f);
  if (t == 0) {
    float2* dinfo = (float2*)(ws + WS_DINFO_F);
    dinfo[d] = make_float2(base, scale);
  }
  #pragma unroll
  for (int h = 0; h < 2; ++h) {
    int cell = t + h*256;
    float target = base + (float)cell * (maxv - base) * (1.0f/(float)NCELL);
    int lo = 0, hi = 257;
    while (lo < hi) { int mid = (lo+hi)>>1; if (arr[mid] < target) lo = mid+1; else hi = mid; }
    ((unsigned short*)(ws + WS_LUT_F))[d*NCELL + cell] = (unsigned short)lo;
  }
}

// ---------- main fused kernel: 8 rows/wave, DPP reductions, packed fp32 math ----------
// r11: r10 + v_pk_fma_f32. Busy-side decomposition: 97k VALU instr/wave at 58% busy;
// only ~37k are algorithmic FMA. The three GEMM/GEMV loops accumulate into INDEPENDENT
// per-accumulator chains -> packing (pairs of accumulators) into <2 x float> fmuladd
// (LLVM -> v_pk_fma_f32, gfx90a+) halves their instruction count with BIT-EXACT
// results (no reassociation; absmax must stay 4.8828e-4 exactly). ~31k FMA -> ~15.5k
// pk_fma. HW question this round answers: pk issue rate on gfx950 (full-rate -> ~-30us;
// half-rate -> flat, revert).
__global__ __launch_bounds__(256, 2)
void mac_fused(const float* __restrict__ hs, const float* __restrict__ eps,
               const float* __restrict__ WQ, const float* __restrict__ bQ,
               const float* __restrict__ WK, const float* __restrict__ bK,
               const float* __restrict__ Wmu, const float* __restrict__ bmu,
               const float* __restrict__ Wvar, const float* __restrict__ bvar,
               const float* __restrict__ vocab,
               const float* __restrict__ Wsum, const float* __restrict__ bsum,
               const float* __restrict__ Whead, const float* __restrict__ bhead,
               const float* __restrict__ ws, float* __restrict__ out, int Btot)
{
  // 71,936 B LDS -> 2 blocks/CU
  __shared__ __align__(16) float ha[ROWSB*HAS];       // wave-private rows; end: comm/o1 alias
  __shared__ __align__(16) float vbuf[ROWSB*HAS];     // V, wave-private, written once
  __shared__ __align__(16) float tokbuf[ROWSB*TBSTR]; // wave-private rows
  __shared__ float ivbuf[ROWSB], finbuf[ROWSB];       // wave-private rows

  const int t   = threadIdx.x;
  const int c4  = t & 63;
  const int w   = t >> 6;         // wave id; rows w*8..w*8+7 (one agent group)
  const int rp  = t >> 4;         // sampling row-pair: rows 2rp, 2rp+1 (in own octet)
  const int dp  = t & 15;         // sampling dim-pair: dims 2dp, 2dp+1
  const int d0u = (c4 << 2) & 31;
  const int tg  = c4 >> 3;        // token slot of this thread's cols
  const int rowbase = blockIdx.x * ROWSB;

  v2f Qp[8][2], Kp[8][2];         // packed persistent state (bit-exact pairs)
  float MSGr[8][4];
  float eosv[4];
  unsigned fin = 0u;

  // ---------------- staging (all wave-private) ----------------
  {
    const float* hp = hs + (size_t)(rowbase + w*8)*HIDN + c4*4;
    #pragma unroll
    for (int rr = 0; rr < 8; ++rr)
      *(float4*)&ha[(w*8+rr)*HAS + c4*4] = *(const float4*)(hp + (size_t)rr*HIDN);
  }
  if (c4 < 8) finbuf[w*8 + c4] = 0.f;
  ld4(eosv, vocab + 256*32 + d0u);
  float dbr[2], dsr[2];
  {
    float t0[4];
    ld4(t0, ws + WS_DINFO_F + dp*4);   // dinfo[2dp], dinfo[2dp+1]
    dbr[0]=t0[0]; dsr[0]=t0[1]; dbr[1]=t0[2]; dsr[1]=t0[3];
  }
  float bm[2], bv[2];
  ld2(bm, bmu + dp*2); ld2(bv, bvar + dp*2);
  lds_fence();   // own-wave ha writes ordered before cross-lane reads

  // ------------- initial GEMM: Q = hs@WQ + bQ ; V = hs@WK + bK (V -> vbuf) -------------
  {
    v2f Vp[8][2];
    {
      float bq[4], bk[4];
      ld4(bq, bQ + c4*4); ld4(bk, bK + c4*4);
      #pragma unroll
      for (int rr = 0; rr < 8; ++rr) {
        Qp[rr][0] = (v2f){bq[0], bq[1]}; Qp[rr][1] = (v2f){bq[2], bq[3]};
        Vp[rr][0] = (v2f){bk[0], bk[1]}; Vp[rr][1] = (v2f){bk[2], bk[3]};
      }
    }
    #pragma unroll 2
    for (int jq = 0; jq < 64; ++jq) {
      float hsq[8][4];
      #pragma unroll
      for (int rr = 0; rr < 8; ++rr) ld4(hsq[rr], &ha[(w*8+rr)*HAS + jq*4]);
      #pragma unroll
      for (int m = 0; m < 4; ++m) {
        float wq[4], wk[4];
        ld4(wq, WQ + (size_t)(jq*4+m)*HIDN + c4*4);
        ld4(wk, WK + (size_t)(jq*4+m)*HIDN + c4*4);
        v2f wq01 = {wq[0], wq[1]}, wq23 = {wq[2], wq[3]};
        v2f wk01 = {wk[0], wk[1]}, wk23 = {wk[2], wk[3]};
        #pragma unroll
        for (int rr = 0; rr < 8; ++rr) {
          v2f h = {hsq[rr][m], hsq[rr][m]};
          Qp[rr][0] += h*wq01; Qp[rr][1] += h*wq23;
          Vp[rr][0] += h*wk01; Vp[rr][1] += h*wk23;
        }
      }
    }
    // park V in LDS (same lane writes and later reads these addresses)
    #pragma unroll
    for (int rr = 0; rr < 8; ++rr)
      *(float4*)&vbuf[(w*8+rr)*HAS + c4*4] =
          make_float4(Vp[rr][0].x, Vp[rr][0].y, Vp[rr][1].x, Vp[rr][1].y);
  }
  {
    float bk[4]; ld4(bk, bK + c4*4);
    const v2f nf2 = {1.0f/256.0f, 1.0f/256.0f};   // bake NF^2: logit = -(Q*K)
    #pragma unroll
    for (int rr = 0; rr < 8; ++rr) {
      Qp[rr][0] *= nf2; Qp[rr][1] *= nf2;
      Kp[rr][0] = (v2f){bk[0], bk[1]}; Kp[rr][1] = (v2f){bk[2], bk[3]};
      #pragma unroll
      for (int k = 0; k < 4; ++k) MSGr[rr][k] = 0.f;
    }
  }
  lds_fence();

  // ---------------- token recurrence (wave-private; zero block barriers) ----------------
  for (int it = 0; it < TT; ++it) {
    if (it > 0) {
      const float* Wr = WK + (size_t)((it-1)*32)*HIDN + c4*4;
      #pragma unroll 2
      for (int cq = 0; cq < 8; ++cq) {
        float tq[8][4];
        #pragma unroll
        for (int rr = 0; rr < 8; ++rr) ld4(tq[rr], &tokbuf[(w*8+rr)*TBSTR + cq*4]);
        #pragma unroll
        for (int m = 0; m < 4; ++m) {
          float wv[4]; ld4(wv, Wr + (size_t)(cq*4+m)*HIDN);
          v2f w01 = {wv[0], wv[1]}, w23 = {wv[2], wv[3]};
          #pragma unroll
          for (int rr = 0; rr < 8; ++rr) {
            v2f h = {tq[rr][m], tq[rr][m]};
            Kp[rr][0] += h*w01; Kp[rr][1] += h*w23;
          }
        }
      }
    }

    // eps prefetch for both sampling rows
    float ep0[2], ep1[2];
    ld2(ep0, eps + ((size_t)it*Btot + rowbase + 2*rp)*32 + dp*2);
    ld2(ep1, eps + ((size_t)it*Btot + rowbase + 2*rp+1)*32 + dp*2);

    // --- softmax(-(Q*K)) without max-sub (|logit|<~2e-3); store e*V; 1/s in ivbuf ---
    #pragma unroll
    for (int rr = 0; rr < 8; ++rr) {
      v2f l0 = Qp[rr][0]*Kp[rr][0];     // pk_mul
      v2f l1 = Qp[rr][1]*Kp[rr][1];
      float e0 = __expf(-l0.x), e1 = __expf(-l0.y);
      float e2 = __expf(-l1.x), e3 = __expf(-l1.y);
      float s = wave_sum64(e0+e1+e2+e3);   // uniform across the wave
      if (c4 == rr) ivbuf[w*8+rr] = 1.0f / s;
      float vv[4];
      ld4(vv, &vbuf[(w*8+rr)*HAS + c4*4]);   // own-lane V readback
      *(float4*)&ha[(w*8+rr)*HAS + c4*4] =
          make_float4(e0*vv[0], e1*vv[1], e2*vv[2], e3*vv[3]);
    }
    lds_fence();

    // --- GEMV (2 rows x 2 dims/thread; 4-j dbuf weight stream; packed accumulators) ---
    v2f A00 = {0,0}, A01 = {0,0}, A10 = {0,0}, A11 = {0,0};
    {
      const float* wmv  = ws + WS_WMV_F + dp*4;   // + j*64 per weight row j
      const float* har0 = &ha[(2*rp)*HAS];
      const float* har1 = &ha[(2*rp+1)*HAS];
      float4 wb0[4], wb1[4];
      #pragma unroll
      for (int u = 0; u < 4; ++u) wb0[u] = *(const float4*)(wmv + (size_t)u*64);
      #pragma unroll 1
      for (int bb = 0; bb < 32; ++bb) {
        {   // window b = 2bb (j = 4b..4b+3, weights in wb0); prefetch b+1 into wb1
          const int b = 2*bb;
          float4 h0 = *(const float4*)(har0 + b*4);
          float4 h1 = *(const float4*)(har1 + b*4);
          const float* wp = wmv + (size_t)(b+1)*256;
          #pragma unroll
          for (int u = 0; u < 4; ++u) wb1[u] = *(const float4*)(wp + (size_t)u*64);
          fma8p(wb0[0], h0.x, h1.x, A00, A01, A10, A11);
          fma8p(wb0[1], h0.y, h1.y, A00, A01, A10, A11);
          fma8p(wb0[2], h0.z, h1.z, A00, A01, A10, A11);
          fma8p(wb0[3], h0.w, h1.w, A00, A01, A10, A11);
        }
        {   // window b = 2bb+1 (weights in wb1); prefetch b+1 into wb0
          const int b = 2*bb+1;
          float4 h0 = *(const float4*)(har0 + b*4);
          float4 h1 = *(const float4*)(har1 + b*4);
          if (bb < 31) {
            const float* wp = wmv + (size_t)(b+1)*256;
            #pragma unroll
            for (int u = 0; u < 4; ++u) wb0[u] = *(const float4*)(wp + (size_t)u*64);
          }
          fma8p(wb1[0], h0.x, h1.x, A00, A01, A10, A11);
          fma8p(wb1[1], h0.y, h1.y, A00, A01, A10, A11);
          fma8p(wb1[2], h0.z, h1.z, A00, A01, A10, A11);
          fma8p(wb1[3], h0.w, h1.w, A00, A01, A10, A11);
        }
      }
    }
    // --- sample + quantize via sorted scan (global, L2-hot, NCELL=512) ---
    {
      float mu0[2] = {A00.x, A01.x}, lv0[2] = {A00.y, A01.y};
      float mu1[2] = {A10.x, A11.x}, lv1[2] = {A10.y, A11.y};
      float ivr0 = ivbuf[2*rp],  ivr1 = ivbuf[2*rp+1];
      float msk0 = 1.0f - finbuf[2*rp], msk1 = 1.0f - finbuf[2*rp+1];
      const unsigned short* lutg = (const unsigned short*)(ws + WS_LUT_F);
      float md0[2], md1[2];
      #pragma unroll
      for (int d = 0; d < 2; ++d) {
        const int dim = 2*dp + d;
        const float* sp = ws + dim*SVS;
        {
          float mu = mu0[d]*ivr0 + bm[d];
          float lv = lv0[d]*ivr0 + bv[d];
          float x  = ep0[d]*__expf(0.5f*lv) + mu;
          int c = (int)((x - dbr[d]) * dsr[d]);
          c = min(max(c, 0), NCELL-1);
          int idx = (int)lutg[dim*NCELL + c];
          float v = sp[idx];
          while (v < x) { ++idx; v = sp[idx]; }   // pads +INF -> terminates
          float dn = v - x;
          float dpv = (idx > 0) ? (x - sp[idx-1]) : 3.0e38f;
          md0[d] = fminf(dn, dpv);
        }
        {
          float mu = mu1[d]*ivr1 + bm[d];
          float lv = lv1[d]*ivr1 + bv[d];
          float x  = ep1[d]*__expf(0.5f*lv) + mu;
          int c = (int)((x - dbr[d]) * dsr[d]);
          c = min(max(c, 0), NCELL-1);
          int idx = (int)lutg[dim*NCELL + c];
          float v = sp[idx];
          while (v < x) { ++idx; v = sp[idx]; }
          float dn = v - x;
          float dpv = (idx > 0) ? (x - sp[idx-1]) : 3.0e38f;
          md1[d] = fminf(dn, dpv);
        }
      }
      *(float2*)&tokbuf[(2*rp)*TBSTR + dp*2]   = make_float2(md0[0]*md0[0]*msk0, md0[1]*md0[1]*msk0);
      *(float2*)&tokbuf[(2*rp+1)*TBSTR + dp*2] = make_float2(md1[0]*md1[0]*msk1, md1[1]*md1[1]*msk1);
    }
    lds_fence();

    // --- hit detection + message update (DPP 8-lane sums, top-lane ballot) ---
    {
      float tokr[8][4];
      #pragma unroll
      for (int rr = 0; rr < 8; ++rr) ld4(tokr[rr], &tokbuf[(w*8+rr)*TBSTR + d0u]);
      const bool top = ((c4 & 7) == 7);   // only top lane of each 8-lane tg group has clean sums
      unsigned newfin = fin;
      #pragma unroll
      for (int rr = 0; rr < 8; ++rr) {
        float pd = 0.f, ed = 0.f;
        #pragma unroll
        for (int k = 0; k < 4; ++k) { float dm = tokr[rr][k]-MSGr[rr][k]; pd += dm*dm; }
        if (tg == 0) {
          #pragma unroll
          for (int k = 0; k < 4; ++k) { float de = tokr[rr][k]-eosv[k]; ed += de*de; }
        }
        pd = grp8_sum(pd);   // valid at top lanes only
        ed = grp8_sum(ed);
        bool lane_hit = top && ((tg < it && pd < EPSI) || (tg == 0 && ed < EPSI));
        bool hit = (__ballot(lane_hit) != 0ull);
        if (hit) {
          if ((tg == it) && !((fin >> rr) & 1u)) {
            #pragma unroll
            for (int k = 0; k < 4; ++k) tokr[rr][k] = eosv[k];
          }
          newfin |= (1u << rr);
        }
        if (tg == it) {
          #pragma unroll
          for (int k = 0; k < 4; ++k) MSGr[rr][k] = tokr[rr][k];
        }
      }
      if (tg == it) {
        #pragma unroll
        for (int rr = 0; rr < 8; ++rr)
          *(float4*)&tokbuf[(w*8+rr)*TBSTR + d0u] =
              make_float4(MSGr[rr][0], MSGr[rr][1], MSGr[rr][2], MSGr[rr][3]);
      }
      if (c4 < 8) finbuf[w*8+c4] = ((newfin >> c4) & 1u) ? 1.f : 0.f;
      fin = newfin;
    }
    lds_fence();
  }

  // ---------------- final: comm sum + two block-coop GEMVs + relu ----------------
  __syncthreads();                 // all waves done with ha before aliasing
  float* commb = ha;               // [4][HAS] rows 0..3
  float* o1    = ha + 4*HAS;       // [4][HAS] rows 4..7
  {
    float cs[4] = {0,0,0,0};
    #pragma unroll
    for (int rr = 0; rr < 8; ++rr) {
      #pragma unroll
      for (int k = 0; k < 4; ++k) cs[k] += MSGr[rr][k];
    }
    const float i7 = 1.0f/7.0f;
    *(float4*)&commb[w*HAS + c4*4] = make_float4(cs[0]*i7, cs[1]*i7, cs[2]*i7, cs[3]*i7);
  }
  __syncthreads();
  {
    float bs = bsum[t];
    float a1[4] = {bs, bs, bs, bs};
    #pragma unroll 2
    for (int jq = 0; jq < 64; ++jq) {
      float w4[4];
      #pragma unroll
      for (int m = 0; m < 4; ++m) w4[m] = Wsum[(size_t)(jq*4+m)*HIDN + t];
      #pragma unroll
      for (int g = 0; g < 4; ++g) {
        float c[4]; ld4(c, &commb[g*HAS + jq*4]);   // uniform broadcast
        a1[g] += c[0]*w4[0] + c[1]*w4[1] + c[2]*w4[2] + c[3]*w4[3];
      }
    }
    #pragma unroll
    for (int g = 0; g < 4; ++g) o1[g*HAS + t] = a1[g];
  }
  __syncthreads();
  {
    float bh = bhead[t];
    float a2[4] = {bh, bh, bh, bh};
    #pragma unroll 2
    for (int jq = 0; jq < 64; ++jq) {
      float w4[4];
      #pragma unroll
      for (int m = 0; m < 4; ++m) w4[m] = Whead[(size_t)(jq*4+m)*HIDN + t];
      #pragma unroll
      for (int g = 0; g < 4; ++g) {
        float c[4]; ld4(c, &o1[g*HAS + jq*4]);
        a2[g] += c[0]*w4[0] + c[1]*w4[1] + c[2]*w4[2] + c[3]*w4[3];
      }
    }
    #pragma unroll
    for (int g = 0; g < 4; ++g) {
      float r = fmaxf(a2[g], 0.f);
      #pragma unroll
      for (int rr = 0; rr < 8; ++rr)
        out[(size_t)(rowbase + g*8 + rr)*HIDN + t] = r;
    }
  }
}

extern "C" void kernel_launch(void* const* d_in, const int* in_sizes, int n_in,
                              void* d_out, int out_size, void* d_ws, size_t ws_size,
                              hipStream_t stream) {
    const float* hs    = (const float*)d_in[0];
    const float* eps   = (const float*)d_in[1];
    const float* WQ    = (const float*)d_in[2];
    const float* bQ    = (const float*)d_in[3];
    const float* WK    = (const float*)d_in[4];
    const float* bK    = (const float*)d_in[5];
    const float* Wmu   = (const float*)d_in[6];
    const float* bmu   = (const float*)d_in[7];
    const float* Wvar  = (const float*)d_in[8];
    const float* bvar  = (const float*)d_in[9];
    const float* vocab = (const float*)d_in[10];
    const float* Wsum  = (const float*)d_in[11];
    const float* bsum  = (const float*)d_in[12];
    const float* Whead = (const float*)d_in[13];
    const float* bhead = (const float*)d_in[14];
    float* o = (float*)d_out;
    float* wsf = (float*)d_ws;
    int Btot = in_sizes[0] / HIDN;
    hipLaunchKernelGGL(sort_vocab, dim3(32), dim3(256), 0, stream, vocab, Wmu, Wvar, wsf);
    hipLaunchKernelGGL(mac_fused, dim3(Btot / ROWSB), dim3(256), 0, stream,
                       hs, eps, WQ, bQ, WK, bK, Wmu, bmu, Wvar, bvar,
                       vocab, Wsum, bsum, Whead, bhead, wsf, o, Btot);
}

// Round 12
// 354.489 us; speedup vs baseline: 1.0145x; 1.0145x over previous
//
#include <hip/hip_runtime.h>

#define ROWSB 32     // rows per block; 4 waves x 8 rows (wave == agent group)
#define HIDN 256
#define TT 8
#define EPSI 1e-6f
#define HAS 260      // ha/vbuf row stride (floats)
#define SVS 260      // sorted-vocab row stride in ws (257 used + 3 INF pad)
#define TBSTR 40
#define NCELL 512
#define WS_LUT_F   (32*SVS)                 // ushort lut[32][512] == 8192 floats
#define WS_DINFO_F (32*SVS + 8192)          // float2 dinfo[32] (base, scale)
#define WS_WMV_F   (32*SVS + 8192 + 64)     // interleaved [j][d][(mu,var)] = 16384 floats

__device__ __forceinline__ void ld4(float* d, const float* p) {
  float4 v = *(const float4*)p;
  d[0] = v.x; d[1] = v.y; d[2] = v.z; d[3] = v.w;
}
__device__ __forceinline__ void ld2(float* d, const float* p) {
  float2 v = *(const float2*)p;
  d[0] = v.x; d[1] = v.y;
}
// Order own-wave LDS write->read without draining the global-load (vmcnt) queue.
// (lgkmcnt-only: global prefetches issued BEFORE this fence stay in flight across it.)
__device__ __forceinline__ void lds_fence() {
  asm volatile("s_waitcnt lgkmcnt(0)" ::: "memory");
}
// 8 FMAs for one j: wv = (mu[d0],var[d0],mu[d1],var[d1]); h0/h1 = ha[row0/1][j]
__device__ __forceinline__ void fma8(float4 wv, float h0, float h1,
                                     float* mu0, float* lv0, float* mu1, float* lv1) {
  mu0[0] += h0*wv.x; lv0[0] += h0*wv.y; mu0[1] += h0*wv.z; lv0[1] += h0*wv.w;
  mu1[0] += h1*wv.x; lv1[0] += h1*wv.y; mu1[1] += h1*wv.z; lv1[1] += h1*wv.w;
}

// ---- DPP cross-lane reductions (pure VALU, zero lgkm) ----
#define DPP_ADD(x, ctrl) \
  (x) += __int_as_float(__builtin_amdgcn_update_dpp(0, __float_as_int(x), (ctrl), 0xf, 0xf, true))
__device__ __forceinline__ float wave_sum64(float x) {
  DPP_ADD(x, 0x111);  // row_shr:1
  DPP_ADD(x, 0x112);  // row_shr:2
  DPP_ADD(x, 0x114);  // row_shr:4
  DPP_ADD(x, 0x118);  // row_shr:8
  DPP_ADD(x, 0x142);  // row_bcast:15
  DPP_ADD(x, 0x143);  // row_bcast:31 -> lane63 = sum(0..63)
  return __int_as_float(__builtin_amdgcn_readlane(__float_as_int(x), 63));
}
// 8-lane group sum: valid ONLY at top lane of each group (c4 & 7) == 7.
__device__ __forceinline__ float grp8_sum(float x) {
  DPP_ADD(x, 0x111);
  DPP_ADD(x, 0x112);
  DPP_ADD(x, 0x114);
  return x;
}

// ---------- pre-pass: per-dim bitonic sort + 512-cell LUT + (mu,var) weight interleave ----------
__global__ __launch_bounds__(256)
void sort_vocab(const float* __restrict__ vocab,
                const float* __restrict__ Wmu, const float* __restrict__ Wvar,
                float* __restrict__ ws) {
  __shared__ float arr[512];
  const int d = blockIdx.x;
  const int t = threadIdx.x;
  ws[WS_WMV_F + ((size_t)t*32 + d)*2 + 0] = Wmu[(size_t)t*32 + d];
  ws[WS_WMV_F + ((size_t)t*32 + d)*2 + 1] = Wvar[(size_t)t*32 + d];
  arr[t] = (t < 257) ? vocab[t*32 + d] : 3.0e38f;
  arr[t+256] = (t == 0) ? vocab[256*32 + d] : 3.0e38f;
  __syncthreads();
  for (int k = 2; k <= 512; k <<= 1) {
    for (int j = k >> 1; j > 0; j >>= 1) {
      #pragma unroll
      for (int h = 0; h < 2; ++h) {
        int i = t + h*256;
        int ixj = i ^ j;
        if (ixj > i) {
          float a = arr[i], b = arr[ixj];
          bool up = ((i & k) == 0);
          if ((a > b) == up) { arr[i] = b; arr[ixj] = a; }
        }
      }
      __syncthreads();
    }
  }
  #pragma unroll
  for (int h = 0; h < 2; ++h) {
    int i = t + h*256;
    if (i < SVS) ws[d*SVS + i] = (i < 257) ? arr[i] : 3.0e38f;
  }
  float base = arr[0];
  float maxv = arr[256];
  float scale = (float)NCELL / fmaxf(maxv - base, 1e-30f);
  if (t == 0) {
    float2* dinfo = (float2*)(ws + WS_DINFO_F);
    dinfo[d] = make_float2(base, scale);
  }
  #pragma unroll
  for (int h = 0; h < 2; ++h) {
    int cell = t + h*256;
    float target = base + (float)cell * (maxv - base) * (1.0f/(float)NCELL);
    int lo = 0, hi = 257;
    while (lo < hi) { int mid = (lo+hi)>>1; if (arr[mid] < target) lo = mid+1; else hi = mid; }
    ((unsigned short*)(ws + WS_LUT_F))[d*NCELL + cell] = (unsigned short)lo;
  }
}

// ---------- main fused kernel: 8 rows/wave, DPP reductions, latency-hiding schedule ----------
// r12: r10 base (281us; r11 proved the kernel is LATENCY-bound, not issue-bound: pk_fma
// cut VALUBusy 58->48.5% with dur FLAT). Three latency edits, no arithmetic change:
//  1) GEMV initial weight-window load hoisted ABOVE the softmax loop -- lds_fence is
//     lgkmcnt-only so the 4 global dwordx4 fly during softmax (~400cyc free cover).
//  2) Cross-fence prefetch kw[4] of next iteration's first K-update weight rows,
//     issued before the trailing fence (junction register pressure is low).
//  3) s_setprio(1) around K-update + GEMV FMA bodies: waves are phase-independent
//     (zero block barriers) -- the measured regime where setprio pays.
__global__ __launch_bounds__(256, 2)
void mac_fused(const float* __restrict__ hs, const float* __restrict__ eps,
               const float* __restrict__ WQ, const float* __restrict__ bQ,
               const float* __restrict__ WK, const float* __restrict__ bK,
               const float* __restrict__ Wmu, const float* __restrict__ bmu,
               const float* __restrict__ Wvar, const float* __restrict__ bvar,
               const float* __restrict__ vocab,
               const float* __restrict__ Wsum, const float* __restrict__ bsum,
               const float* __restrict__ Whead, const float* __restrict__ bhead,
               const float* __restrict__ ws, float* __restrict__ out, int Btot)
{
  // 71,936 B LDS -> 2 blocks/CU
  __shared__ __align__(16) float ha[ROWSB*HAS];       // wave-private rows; end: comm/o1 alias
  __shared__ __align__(16) float vbuf[ROWSB*HAS];     // V, wave-private, written once
  __shared__ __align__(16) float tokbuf[ROWSB*TBSTR]; // wave-private rows
  __shared__ float ivbuf[ROWSB], finbuf[ROWSB];       // wave-private rows

  const int t   = threadIdx.x;
  const int c4  = t & 63;
  const int w   = t >> 6;         // wave id; rows w*8..w*8+7 (one agent group)
  const int rp  = t >> 4;         // sampling row-pair: rows 2rp, 2rp+1 (in own octet)
  const int dp  = t & 15;         // sampling dim-pair: dims 2dp, 2dp+1
  const int d0u = (c4 << 2) & 31;
  const int tg  = c4 >> 3;        // token slot of this thread's cols
  const int rowbase = blockIdx.x * ROWSB;

  float Qr[8][4], Kr[8][4], MSGr[8][4];
  float eosv[4];
  unsigned fin = 0u;

  // ---------------- staging (all wave-private) ----------------
  {
    const float* hp = hs + (size_t)(rowbase + w*8)*HIDN + c4*4;
    #pragma unroll
    for (int rr = 0; rr < 8; ++rr)
      *(float4*)&ha[(w*8+rr)*HAS + c4*4] = *(const float4*)(hp + (size_t)rr*HIDN);
  }
  if (c4 < 8) finbuf[w*8 + c4] = 0.f;
  ld4(eosv, vocab + 256*32 + d0u);
  float dbr[2], dsr[2];
  {
    float t0[4];
    ld4(t0, ws + WS_DINFO_F + dp*4);   // dinfo[2dp], dinfo[2dp+1]
    dbr[0]=t0[0]; dsr[0]=t0[1]; dbr[1]=t0[2]; dsr[1]=t0[3];
  }
  float bm[2], bv[2];
  ld2(bm, bmu + dp*2); ld2(bv, bvar + dp*2);
  lds_fence();   // own-wave ha writes ordered before cross-lane reads

  // ------------- initial GEMM: Q = hs@WQ + bQ ; V = hs@WK + bK (V -> vbuf) -------------
  {
    float Vr[8][4];
    {
      float bq[4], bk[4];
      ld4(bq, bQ + c4*4); ld4(bk, bK + c4*4);
      #pragma unroll
      for (int rr = 0; rr < 8; ++rr) {
        #pragma unroll
        for (int k = 0; k < 4; ++k) { Qr[rr][k] = bq[k]; Vr[rr][k] = bk[k]; }
      }
    }
    #pragma unroll 2
    for (int jq = 0; jq < 64; ++jq) {
      float hsq[8][4];
      #pragma unroll
      for (int rr = 0; rr < 8; ++rr) ld4(hsq[rr], &ha[(w*8+rr)*HAS + jq*4]);
      #pragma unroll
      for (int m = 0; m < 4; ++m) {
        float wq[4], wk[4];
        ld4(wq, WQ + (size_t)(jq*4+m)*HIDN + c4*4);
        ld4(wk, WK + (size_t)(jq*4+m)*HIDN + c4*4);
        #pragma unroll
        for (int rr = 0; rr < 8; ++rr) {
          #pragma unroll
          for (int k = 0; k < 4; ++k) {
            Qr[rr][k] += hsq[rr][m]*wq[k];
            Vr[rr][k] += hsq[rr][m]*wk[k];
          }
        }
      }
    }
    // park V in LDS (same lane writes and later reads these addresses)
    #pragma unroll
    for (int rr = 0; rr < 8; ++rr)
      *(float4*)&vbuf[(w*8+rr)*HAS + c4*4] =
          make_float4(Vr[rr][0], Vr[rr][1], Vr[rr][2], Vr[rr][3]);
  }
  {
    float bk[4]; ld4(bk, bK + c4*4);
    #pragma unroll
    for (int rr = 0; rr < 8; ++rr) {
      #pragma unroll
      for (int k = 0; k < 4; ++k) {
        Qr[rr][k] *= (1.0f/256.0f);   // bake NF^2: logit = -(Qr*Kr)
        Kr[rr][k]   = bk[k];
        MSGr[rr][k] = 0.f;
      }
    }
  }
  lds_fence();

  const float* wmv = ws + WS_WMV_F + dp*4;   // GEMV weight stream base (+ j*64 per row j)
  float4 kw[4];                              // cross-fence K-update weight prefetch (cq=0)

  // ---------------- token recurrence (wave-private; zero block barriers) ----------------
  for (int it = 0; it < TT; ++it) {
    if (it > 0) {
      const float* Wr = WK + (size_t)((it-1)*32)*HIDN + c4*4;
      __builtin_amdgcn_s_setprio(1);
      #pragma unroll 2
      for (int cq = 0; cq < 8; ++cq) {
        float tq[8][4];
        #pragma unroll
        for (int rr = 0; rr < 8; ++rr) ld4(tq[rr], &tokbuf[(w*8+rr)*TBSTR + cq*4]);
        #pragma unroll
        for (int m = 0; m < 4; ++m) {
          float wv[4];
          if (cq == 0) { wv[0]=kw[m].x; wv[1]=kw[m].y; wv[2]=kw[m].z; wv[3]=kw[m].w; }
          else          ld4(wv, Wr + (size_t)(cq*4+m)*HIDN);
          #pragma unroll
          for (int rr = 0; rr < 8; ++rr) {
            #pragma unroll
            for (int k = 0; k < 4; ++k) Kr[rr][k] += tq[rr][m]*wv[k];
          }
        }
      }
      __builtin_amdgcn_s_setprio(0);
    }

    // eps prefetch for both sampling rows
    float ep0[2], ep1[2];
    ld2(ep0, eps + ((size_t)it*Btot + rowbase + 2*rp)*32 + dp*2);
    ld2(ep1, eps + ((size_t)it*Btot + rowbase + 2*rp+1)*32 + dp*2);

    // GEMV weight window 0 prefetch -- issued BEFORE softmax; lands during it (vmcnt
    // not drained by lds_fence). Removes the per-iteration GEMV head stall.
    float4 wb0[4], wb1[4];
    #pragma unroll
    for (int u = 0; u < 4; ++u) wb0[u] = *(const float4*)(wmv + (size_t)u*64);

    // --- softmax(-(Q*K)) without max-sub (|logit|<~2e-3); store e*V; 1/s in ivbuf ---
    #pragma unroll
    for (int rr = 0; rr < 8; ++rr) {
      float e[4]; float p = 0.f;
      #pragma unroll
      for (int k = 0; k < 4; ++k) { e[k] = __expf(-(Qr[rr][k]*Kr[rr][k])); p += e[k]; }
      float s = wave_sum64(p);           // uniform across the wave
      if (c4 == rr) ivbuf[w*8+rr] = 1.0f / s;
      float vv[4];
      ld4(vv, &vbuf[(w*8+rr)*HAS + c4*4]);   // own-lane V readback
      *(float4*)&ha[(w*8+rr)*HAS + c4*4] =
          make_float4(e[0]*vv[0], e[1]*vv[1], e[2]*vv[2], e[3]*vv[3]);
    }
    lds_fence();

    // --- GEMV (2 rows x 2 dims/thread; 4-j double-buffered weight stream, 32 regs) ---
    float mu0[2]={0,0}, lv0[2]={0,0}, mu1[2]={0,0}, lv1[2]={0,0};
    {
      const float* har0 = &ha[(2*rp)*HAS];
      const float* har1 = &ha[(2*rp+1)*HAS];
      __builtin_amdgcn_s_setprio(1);
      #pragma unroll 1
      for (int bb = 0; bb < 32; ++bb) {
        {   // window b = 2bb (j = 4b..4b+3, weights in wb0); prefetch b+1 into wb1
          const int b = 2*bb;
          float4 h0 = *(const float4*)(har0 + b*4);
          float4 h1 = *(const float4*)(har1 + b*4);
          const float* wp = wmv + (size_t)(b+1)*256;
          #pragma unroll
          for (int u = 0; u < 4; ++u) wb1[u] = *(const float4*)(wp + (size_t)u*64);
          fma8(wb0[0], h0.x, h1.x, mu0, lv0, mu1, lv1);
          fma8(wb0[1], h0.y, h1.y, mu0, lv0, mu1, lv1);
          fma8(wb0[2], h0.z, h1.z, mu0, lv0, mu1, lv1);
          fma8(wb0[3], h0.w, h1.w, mu0, lv0, mu1, lv1);
        }
        {   // window b = 2bb+1 (weights in wb1); prefetch b+1 into wb0
          const int b = 2*bb+1;
          float4 h0 = *(const float4*)(har0 + b*4);
          float4 h1 = *(const float4*)(har1 + b*4);
          if (bb < 31) {
            const float* wp = wmv + (size_t)(b+1)*256;
            #pragma unroll
            for (int u = 0; u < 4; ++u) wb0[u] = *(const float4*)(wp + (size_t)u*64);
          }
          fma8(wb1[0], h0.x, h1.x, mu0, lv0, mu1, lv1);
          fma8(wb1[1], h0.y, h1.y, mu0, lv0, mu1, lv1);
          fma8(wb1[2], h0.z, h1.z, mu0, lv0, mu1, lv1);
          fma8(wb1[3], h0.w, h1.w, mu0, lv0, mu1, lv1);
        }
      }
      __builtin_amdgcn_s_setprio(0);
    }
    // --- sample + quantize via sorted scan (global, L2-hot, NCELL=512) ---
    {
      float ivr0 = ivbuf[2*rp],  ivr1 = ivbuf[2*rp+1];
      float msk0 = 1.0f - finbuf[2*rp], msk1 = 1.0f - finbuf[2*rp+1];
      const unsigned short* lutg = (const unsigned short*)(ws + WS_LUT_F);
      float md0[2], md1[2];
      #pragma unroll
      for (int d = 0; d < 2; ++d) {
        const int dim = 2*dp + d;
        const float* sp = ws + dim*SVS;
        {
          float mu = mu0[d]*ivr0 + bm[d];
          float lv = lv0[d]*ivr0 + bv[d];
          float x  = ep0[d]*__expf(0.5f*lv) + mu;
          int c = (int)((x - dbr[d]) * dsr[d]);
          c = min(max(c, 0), NCELL-1);
          int idx = (int)lutg[dim*NCELL + c];
          float v = sp[idx];
          while (v < x) { ++idx; v = sp[idx]; }   // pads +INF -> terminates
          float dn = v - x;
          float dpv = (idx > 0) ? (x - sp[idx-1]) : 3.0e38f;
          md0[d] = fminf(dn, dpv);
        }
        {
          float mu = mu1[d]*ivr1 + bm[d];
          float lv = lv1[d]*ivr1 + bv[d];
          float x  = ep1[d]*__expf(0.5f*lv) + mu;
          int c = (int)((x - dbr[d]) * dsr[d]);
          c = min(max(c, 0), NCELL-1);
          int idx = (int)lutg[dim*NCELL + c];
          float v = sp[idx];
          while (v < x) { ++idx; v = sp[idx]; }
          float dn = v - x;
          float dpv = (idx > 0) ? (x - sp[idx-1]) : 3.0e38f;
          md1[d] = fminf(dn, dpv);
        }
      }
      *(float2*)&tokbuf[(2*rp)*TBSTR + dp*2]   = make_float2(md0[0]*md0[0]*msk0, md0[1]*md0[1]*msk0);
      *(float2*)&tokbuf[(2*rp+1)*TBSTR + dp*2] = make_float2(md1[0]*md1[0]*msk1, md1[1]*md1[1]*msk1);
    }
    lds_fence();

    // --- hit detection + message update (DPP 8-lane sums, top-lane ballot) ---
    {
      float tokr[8][4];
      #pragma unroll
      for (int rr = 0; rr < 8; ++rr) ld4(tokr[rr], &tokbuf[(w*8+rr)*TBSTR + d0u]);
      const bool top = ((c4 & 7) == 7);   // only top lane of each 8-lane tg group has clean sums
      unsigned newfin = fin;
      #pragma unroll
      for (int rr = 0; rr < 8; ++rr) {
        float pd = 0.f, ed = 0.f;
        #pragma unroll
        for (int k = 0; k < 4; ++k) { float dm = tokr[rr][k]-MSGr[rr][k]; pd += dm*dm; }
        if (tg == 0) {
          #pragma unroll
          for (int k = 0; k < 4; ++k) { float de = tokr[rr][k]-eosv[k]; ed += de*de; }
        }
        pd = grp8_sum(pd);   // valid at top lanes only
        ed = grp8_sum(ed);
        bool lane_hit = top && ((tg < it && pd < EPSI) || (tg == 0 && ed < EPSI));
        bool hit = (__ballot(lane_hit) != 0ull);
        if (hit) {
          if ((tg == it) && !((fin >> rr) & 1u)) {
            #pragma unroll
            for (int k = 0; k < 4; ++k) tokr[rr][k] = eosv[k];
          }
          newfin |= (1u << rr);
        }
        if (tg == it) {
          #pragma unroll
          for (int k = 0; k < 4; ++k) MSGr[rr][k] = tokr[rr][k];
        }
      }
      if (tg == it) {
        #pragma unroll
        for (int rr = 0; rr < 8; ++rr)
          *(float4*)&tokbuf[(w*8+rr)*TBSTR + d0u] =
              make_float4(MSGr[rr][0], MSGr[rr][1], MSGr[rr][2], MSGr[rr][3]);
      }
      if (c4 < 8) finbuf[w*8+c4] = ((newfin >> c4) & 1u) ? 1.f : 0.f;
      fin = newfin;
    }
    // cross-fence prefetch: next iteration's first K-update weight rows fly over the
    // trailing fence and the next iteration's tokbuf reads.
    if (it < TT-1) {
      const float* WrN = WK + (size_t)(it*32)*HIDN + c4*4;
      #pragma unroll
      for (int m = 0; m < 4; ++m) kw[m] = *(const float4*)(WrN + (size_t)m*HIDN);
    }
    lds_fence();
  }

  // ---------------- final: comm sum + two block-coop GEMVs + relu ----------------
  __syncthreads();                 // all waves done with ha before aliasing
  float* commb = ha;               // [4][HAS] rows 0..3
  float* o1    = ha + 4*HAS;       // [4][HAS] rows 4..7
  {
    float cs[4] = {0,0,0,0};
    #pragma unroll
    for (int rr = 0; rr < 8; ++rr) {
      #pragma unroll
      for (int k = 0; k < 4; ++k) cs[k] += MSGr[rr][k];
    }
    const float i7 = 1.0f/7.0f;
    *(float4*)&commb[w*HAS + c4*4] = make_float4(cs[0]*i7, cs[1]*i7, cs[2]*i7, cs[3]*i7);
  }
  __syncthreads();
  {
    float bs = bsum[t];
    float a1[4] = {bs, bs, bs, bs};
    #pragma unroll 2
    for (int jq = 0; jq < 64; ++jq) {
      float w4[4];
      #pragma unroll
      for (int m = 0; m < 4; ++m) w4[m] = Wsum[(size_t)(jq*4+m)*HIDN + t];
      #pragma unroll
      for (int g = 0; g < 4; ++g) {
        float c[4]; ld4(c, &commb[g*HAS + jq*4]);   // uniform broadcast
        a1[g] += c[0]*w4[0] + c[1]*w4[1] + c[2]*w4[2] + c[3]*w4[3];
      }
    }
    #pragma unroll
    for (int g = 0; g < 4; ++g) o1[g*HAS + t] = a1[g];
  }
  __syncthreads();
  {
    float bh = bhead[t];
    float a2[4] = {bh, bh, bh, bh};
    #pragma unroll 2
    for (int jq = 0; jq < 64; ++jq) {
      float w4[4];
      #pragma unroll
      for (int m = 0; m < 4; ++m) w4[m] = Whead[(size_t)(jq*4+m)*HIDN + t];
      #pragma unroll
      for (int g = 0; g < 4; ++g) {
        float c[4]; ld4(c, &o1[g*HAS + jq*4]);
        a2[g] += c[0]*w4[0] + c[1]*w4[1] + c[2]*w4[2] + c[3]*w4[3];
      }
    }
    #pragma unroll
    for (int g = 0; g < 4; ++g) {
      float r = fmaxf(a2[g], 0.f);
      #pragma unroll
      for (int rr = 0; rr < 8; ++rr)
        out[(size_t)(rowbase + g*8 + rr)*HIDN + t] = r;
    }
  }
}

extern "C" void kernel_launch(void* const* d_in, const int* in_sizes, int n_in,
                              void* d_out, int out_size, void* d_ws, size_t ws_size,
                              hipStream_t stream) {
    const float* hs    = (const float*)d_in[0];
    const float* eps   = (const float*)d_in[1];
    const float* WQ    = (const float*)d_in[2];
    const float* bQ    = (const float*)d_in[3];
    const float* WK    = (const float*)d_in[4];
    const float* bK    = (const float*)d_in[5];
    const float* Wmu   = (const float*)d_in[6];
    const float* bmu   = (const float*)d_in[7];
    const float* Wvar  = (const float*)d_in[8];
    const float* bvar  = (const float*)d_in[9];
    const float* vocab = (const float*)d_in[10];
    const float* Wsum  = (const float*)d_in[11];
    const float* bsum  = (const float*)d_in[12];
    const float* Whead = (const float*)d_in[13];
    const float* bhead = (const float*)d_in[14];
    float* o = (float*)d_out;
    float* wsf = (float*)d_ws;
    int Btot = in_sizes[0] / HIDN;
    hipLaunchKernelGGL(sort_vocab, dim3(32), dim3(256), 0, stream, vocab, Wmu, Wvar, wsf);
    hipLaunchKernelGGL(mac_fused, dim3(Btot / ROWSB), dim3(256), 0, stream,
                       hs, eps, WQ, bQ, WK, bK, Wmu, bmu, Wvar, bvar,
                       vocab, Wsum, bsum, Whead, bhead, wsf, o, Btot);
}

// Round 13
// 353.136 us; speedup vs baseline: 1.0184x; 1.0038x over previous
//
#include <hip/hip_runtime.h>

#define ROWSB 32     // rows per block; 4 waves x 8 rows (wave == agent group)
#define HIDN 256
#define TT 8
#define EPSI 1e-6f
#define HAS 260      // ha/vbuf row stride (floats)
#define SVS 260      // sorted-vocab row stride in ws (257 used + 3 INF pad)
#define TBSTR 40
#define NCELL 512
#define WS_LUT_F   (32*SVS)                 // ushort lut[32][512] == 8192 floats
#define WS_DINFO_F (32*SVS + 8192)          // float2 dinfo[32] (base, scale)
#define WS_WMV_F   (32*SVS + 8192 + 64)     // interleaved [j][d][(mu,var)] = 16384 floats

__device__ __forceinline__ void ld4(float* d, const float* p) {
  float4 v = *(const float4*)p;
  d[0] = v.x; d[1] = v.y; d[2] = v.z; d[3] = v.w;
}
__device__ __forceinline__ void ld2(float* d, const float* p) {
  float2 v = *(const float2*)p;
  d[0] = v.x; d[1] = v.y;
}
// Order own-wave LDS write->read without draining the global-load (vmcnt) queue.
__device__ __forceinline__ void lds_fence() {
  asm volatile("s_waitcnt lgkmcnt(0)" ::: "memory");
}
// 8 FMAs for one j: wv = (mu[d0],var[d0],mu[d1],var[d1]); h0/h1 = ha[row0/1][j]
__device__ __forceinline__ void fma8(float4 wv, float h0, float h1,
                                     float* mu0, float* lv0, float* mu1, float* lv1) {
  mu0[0] += h0*wv.x; lv0[0] += h0*wv.y; mu0[1] += h0*wv.z; lv0[1] += h0*wv.w;
  mu1[0] += h1*wv.x; lv1[0] += h1*wv.y; mu1[1] += h1*wv.z; lv1[1] += h1*wv.w;
}

// ---- DPP cross-lane reductions (pure VALU, zero lgkm) ----
#define DPP_ADD(x, ctrl) \
  (x) += __int_as_float(__builtin_amdgcn_update_dpp(0, __float_as_int(x), (ctrl), 0xf, 0xf, true))
__device__ __forceinline__ float wave_sum64(float x) {
  DPP_ADD(x, 0x111);  // row_shr:1
  DPP_ADD(x, 0x112);  // row_shr:2
  DPP_ADD(x, 0x114);  // row_shr:4
  DPP_ADD(x, 0x118);  // row_shr:8
  DPP_ADD(x, 0x142);  // row_bcast:15
  DPP_ADD(x, 0x143);  // row_bcast:31 -> lane63 = sum(0..63)
  return __int_as_float(__builtin_amdgcn_readlane(__float_as_int(x), 63));
}
// 8-lane group sum: valid ONLY at top lane of each group (c4 & 7) == 7.
__device__ __forceinline__ float grp8_sum(float x) {
  DPP_ADD(x, 0x111);
  DPP_ADD(x, 0x112);
  DPP_ADD(x, 0x114);
  return x;
}

// ---------- pre-pass: per-dim bitonic sort + 512-cell LUT + (mu,var) weight interleave ----------
__global__ __launch_bounds__(256)
void sort_vocab(const float* __restrict__ vocab,
                const float* __restrict__ Wmu, const float* __restrict__ Wvar,
                float* __restrict__ ws) {
  __shared__ float arr[512];
  const int d = blockIdx.x;
  const int t = threadIdx.x;
  ws[WS_WMV_F + ((size_t)t*32 + d)*2 + 0] = Wmu[(size_t)t*32 + d];
  ws[WS_WMV_F + ((size_t)t*32 + d)*2 + 1] = Wvar[(size_t)t*32 + d];
  arr[t] = (t < 257) ? vocab[t*32 + d] : 3.0e38f;
  arr[t+256] = (t == 0) ? vocab[256*32 + d] : 3.0e38f;
  __syncthreads();
  for (int k = 2; k <= 512; k <<= 1) {
    for (int j = k >> 1; j > 0; j >>= 1) {
      #pragma unroll
      for (int h = 0; h < 2; ++h) {
        int i = t + h*256;
        int ixj = i ^ j;
        if (ixj > i) {
          float a = arr[i], b = arr[ixj];
          bool up = ((i & k) == 0);
          if ((a > b) == up) { arr[i] = b; arr[ixj] = a; }
        }
      }
      __syncthreads();
    }
  }
  #pragma unroll
  for (int h = 0; h < 2; ++h) {
    int i = t + h*256;
    if (i < SVS) ws[d*SVS + i] = (i < 257) ? arr[i] : 3.0e38f;
  }
  float base = arr[0];
  float maxv = arr[256];
  float scale = (float)NCELL / fmaxf(maxv - base, 1e-30f);
  if (t == 0) {
    float2* dinfo = (float2*)(ws + WS_DINFO_F);
    dinfo[d] = make_float2(base, scale);
  }
  #pragma unroll
  for (int h = 0; h < 2; ++h) {
    int cell = t + h*256;
    float target = base + (float)cell * (maxv - base) * (1.0f/(float)NCELL);
    int lo = 0, hi = 257;
    while (lo < hi) { int mid = (lo+hi)>>1; if (arr[mid] < target) lo = mid+1; else hi = mid; }
    ((unsigned short*)(ws + WS_LUT_F))[d*NCELL + cell] = (unsigned short)lo;
  }
}

// ---------- main fused kernel: 8 rows/wave, DPP reductions, zero-cost latency edits ----------
// r13 = r10 (281us best) + ONLY the zero-register-cost pieces of r12 (whose 16+16-reg
// cross-phase prefetches spilled 7MB hot and regressed):
//  1) s_setprio(1) around K-update + GEMV FMA bodies (0 regs; waves phase-independent).
//  2) 1/s + finished-mask register capture (r4-validated): wave_sum64's s is uniform ->
//     each lane keeps 1/s for its own 2 sampling rows; fin register is lane-coherent ->
//     mask derived directly. Deletes ivbuf/finbuf LDS round-trips. Net regs ~0.
// No arithmetic change -> absmax must stay exactly 4.8828e-4.
__global__ __launch_bounds__(256, 2)
void mac_fused(const float* __restrict__ hs, const float* __restrict__ eps,
               const float* __restrict__ WQ, const float* __restrict__ bQ,
               const float* __restrict__ WK, const float* __restrict__ bK,
               const float* __restrict__ Wmu, const float* __restrict__ bmu,
               const float* __restrict__ Wvar, const float* __restrict__ bvar,
               const float* __restrict__ vocab,
               const float* __restrict__ Wsum, const float* __restrict__ bsum,
               const float* __restrict__ Whead, const float* __restrict__ bhead,
               const float* __restrict__ ws, float* __restrict__ out, int Btot)
{
  // 71,680 B LDS -> 2 blocks/CU
  __shared__ __align__(16) float ha[ROWSB*HAS];       // wave-private rows; end: comm/o1 alias
  __shared__ __align__(16) float vbuf[ROWSB*HAS];     // V, wave-private, written once
  __shared__ __align__(16) float tokbuf[ROWSB*TBSTR]; // wave-private rows

  const int t   = threadIdx.x;
  const int c4  = t & 63;
  const int w   = t >> 6;         // wave id; rows w*8..w*8+7 (one agent group)
  const int rp  = t >> 4;         // sampling row-pair: block rows 2rp, 2rp+1 (in own octet)
  const int lp  = (t >> 4) & 3;   // local row-pair within wave: local rows 2lp, 2lp+1
  const int dp  = t & 15;         // sampling dim-pair: dims 2dp, 2dp+1
  const int d0u = (c4 << 2) & 31;
  const int tg  = c4 >> 3;        // token slot of this thread's cols
  const int rowbase = blockIdx.x * ROWSB;

  float Qr[8][4], Kr[8][4], MSGr[8][4];
  float eosv[4];
  unsigned fin = 0u;

  // ---------------- staging (all wave-private) ----------------
  {
    const float* hp = hs + (size_t)(rowbase + w*8)*HIDN + c4*4;
    #pragma unroll
    for (int rr = 0; rr < 8; ++rr)
      *(float4*)&ha[(w*8+rr)*HAS + c4*4] = *(const float4*)(hp + (size_t)rr*HIDN);
  }
  ld4(eosv, vocab + 256*32 + d0u);
  float dbr[2], dsr[2];
  {
    float t0[4];
    ld4(t0, ws + WS_DINFO_F + dp*4);   // dinfo[2dp], dinfo[2dp+1]
    dbr[0]=t0[0]; dsr[0]=t0[1]; dbr[1]=t0[2]; dsr[1]=t0[3];
  }
  float bm[2], bv[2];
  ld2(bm, bmu + dp*2); ld2(bv, bvar + dp*2);
  lds_fence();   // own-wave ha writes ordered before cross-lane reads

  // ------------- initial GEMM: Q = hs@WQ + bQ ; V = hs@WK + bK (V -> vbuf) -------------
  {
    float Vr[8][4];
    {
      float bq[4], bk[4];
      ld4(bq, bQ + c4*4); ld4(bk, bK + c4*4);
      #pragma unroll
      for (int rr = 0; rr < 8; ++rr) {
        #pragma unroll
        for (int k = 0; k < 4; ++k) { Qr[rr][k] = bq[k]; Vr[rr][k] = bk[k]; }
      }
    }
    #pragma unroll 2
    for (int jq = 0; jq < 64; ++jq) {
      float hsq[8][4];
      #pragma unroll
      for (int rr = 0; rr < 8; ++rr) ld4(hsq[rr], &ha[(w*8+rr)*HAS + jq*4]);
      #pragma unroll
      for (int m = 0; m < 4; ++m) {
        float wq[4], wk[4];
        ld4(wq, WQ + (size_t)(jq*4+m)*HIDN + c4*4);
        ld4(wk, WK + (size_t)(jq*4+m)*HIDN + c4*4);
        #pragma unroll
        for (int rr = 0; rr < 8; ++rr) {
          #pragma unroll
          for (int k = 0; k < 4; ++k) {
            Qr[rr][k] += hsq[rr][m]*wq[k];
            Vr[rr][k] += hsq[rr][m]*wk[k];
          }
        }
      }
    }
    // park V in LDS (same lane writes and later reads these addresses)
    #pragma unroll
    for (int rr = 0; rr < 8; ++rr)
      *(float4*)&vbuf[(w*8+rr)*HAS + c4*4] =
          make_float4(Vr[rr][0], Vr[rr][1], Vr[rr][2], Vr[rr][3]);
  }
  {
    float bk[4]; ld4(bk, bK + c4*4);
    #pragma unroll
    for (int rr = 0; rr < 8; ++rr) {
      #pragma unroll
      for (int k = 0; k < 4; ++k) {
        Qr[rr][k] *= (1.0f/256.0f);   // bake NF^2: logit = -(Qr*Kr)
        Kr[rr][k]   = bk[k];
        MSGr[rr][k] = 0.f;
      }
    }
  }
  lds_fence();

  // ---------------- token recurrence (wave-private; zero block barriers) ----------------
  for (int it = 0; it < TT; ++it) {
    if (it > 0) {
      const float* Wr = WK + (size_t)((it-1)*32)*HIDN + c4*4;
      __builtin_amdgcn_s_setprio(1);
      #pragma unroll 2
      for (int cq = 0; cq < 8; ++cq) {
        float tq[8][4];
        #pragma unroll
        for (int rr = 0; rr < 8; ++rr) ld4(tq[rr], &tokbuf[(w*8+rr)*TBSTR + cq*4]);
        #pragma unroll
        for (int m = 0; m < 4; ++m) {
          float wv[4]; ld4(wv, Wr + (size_t)(cq*4+m)*HIDN);
          #pragma unroll
          for (int rr = 0; rr < 8; ++rr) {
            #pragma unroll
            for (int k = 0; k < 4; ++k) Kr[rr][k] += tq[rr][m]*wv[k];
          }
        }
      }
      __builtin_amdgcn_s_setprio(0);
    }

    // eps prefetch for both sampling rows
    float ep0[2], ep1[2];
    ld2(ep0, eps + ((size_t)it*Btot + rowbase + 2*rp)*32 + dp*2);
    ld2(ep1, eps + ((size_t)it*Btot + rowbase + 2*rp+1)*32 + dp*2);

    // --- softmax(-(Q*K)) without max-sub (|logit|<~2e-3); store e*V; capture 1/s in regs ---
    float iv0 = 0.f, iv1 = 0.f;
    #pragma unroll
    for (int rr = 0; rr < 8; ++rr) {
      float e[4]; float p = 0.f;
      #pragma unroll
      for (int k = 0; k < 4; ++k) { e[k] = __expf(-(Qr[rr][k]*Kr[rr][k])); p += e[k]; }
      float s = wave_sum64(p);           // uniform across the wave
      if (rr == 2*lp)     iv0 = 1.0f / s;
      if (rr == 2*lp + 1) iv1 = 1.0f / s;
      float vv[4];
      ld4(vv, &vbuf[(w*8+rr)*HAS + c4*4]);   // own-lane V readback
      *(float4*)&ha[(w*8+rr)*HAS + c4*4] =
          make_float4(e[0]*vv[0], e[1]*vv[1], e[2]*vv[2], e[3]*vv[3]);
    }
    lds_fence();

    // --- GEMV (2 rows x 2 dims/thread; 4-j double-buffered weight stream, 32 regs) ---
    float mu0[2]={0,0}, lv0[2]={0,0}, mu1[2]={0,0}, lv1[2]={0,0};
    {
      const float* wmv  = ws + WS_WMV_F + dp*4;   // + j*64 per weight row j
      const float* har0 = &ha[(2*rp)*HAS];
      const float* har1 = &ha[(2*rp+1)*HAS];
      float4 wb0[4], wb1[4];
      #pragma unroll
      for (int u = 0; u < 4; ++u) wb0[u] = *(const float4*)(wmv + (size_t)u*64);
      __builtin_amdgcn_s_setprio(1);
      #pragma unroll 1
      for (int bb = 0; bb < 32; ++bb) {
        {   // window b = 2bb (j = 4b..4b+3, weights in wb0); prefetch b+1 into wb1
          const int b = 2*bb;
          float4 h0 = *(const float4*)(har0 + b*4);
          float4 h1 = *(const float4*)(har1 + b*4);
          const float* wp = wmv + (size_t)(b+1)*256;
          #pragma unroll
          for (int u = 0; u < 4; ++u) wb1[u] = *(const float4*)(wp + (size_t)u*64);
          fma8(wb0[0], h0.x, h1.x, mu0, lv0, mu1, lv1);
          fma8(wb0[1], h0.y, h1.y, mu0, lv0, mu1, lv1);
          fma8(wb0[2], h0.z, h1.z, mu0, lv0, mu1, lv1);
          fma8(wb0[3], h0.w, h1.w, mu0, lv0, mu1, lv1);
        }
        {   // window b = 2bb+1 (weights in wb1); prefetch b+1 into wb0
          const int b = 2*bb+1;
          float4 h0 = *(const float4*)(har0 + b*4);
          float4 h1 = *(const float4*)(har1 + b*4);
          if (bb < 31) {
            const float* wp = wmv + (size_t)(b+1)*256;
            #pragma unroll
            for (int u = 0; u < 4; ++u) wb0[u] = *(const float4*)(wp + (size_t)u*64);
          }
          fma8(wb1[0], h0.x, h1.x, mu0, lv0, mu1, lv1);
          fma8(wb1[1], h0.y, h1.y, mu0, lv0, mu1, lv1);
          fma8(wb1[2], h0.z, h1.z, mu0, lv0, mu1, lv1);
          fma8(wb1[3], h0.w, h1.w, mu0, lv0, mu1, lv1);
        }
      }
      __builtin_amdgcn_s_setprio(0);
    }
    // --- sample + quantize via sorted scan (global, L2-hot, NCELL=512) ---
    {
      float msk0 = ((fin >> (2*lp))   & 1u) ? 0.f : 1.f;
      float msk1 = ((fin >> (2*lp+1)) & 1u) ? 0.f : 1.f;
      const unsigned short* lutg = (const unsigned short*)(ws + WS_LUT_F);
      float md0[2], md1[2];
      #pragma unroll
      for (int d = 0; d < 2; ++d) {
        const int dim = 2*dp + d;
        const float* sp = ws + dim*SVS;
        {
          float mu = mu0[d]*iv0 + bm[d];
          float lv = lv0[d]*iv0 + bv[d];
          float x  = ep0[d]*__expf(0.5f*lv) + mu;
          int c = (int)((x - dbr[d]) * dsr[d]);
          c = min(max(c, 0), NCELL-1);
          int idx = (int)lutg[dim*NCELL + c];
          float v = sp[idx];
          while (v < x) { ++idx; v = sp[idx]; }   // pads +INF -> terminates
          float dn = v - x;
          float dpv = (idx > 0) ? (x - sp[idx-1]) : 3.0e38f;
          md0[d] = fminf(dn, dpv);
        }
        {
          float mu = mu1[d]*iv1 + bm[d];
          float lv = lv1[d]*iv1 + bv[d];
          float x  = ep1[d]*__expf(0.5f*lv) + mu;
          int c = (int)((x - dbr[d]) * dsr[d]);
          c = min(max(c, 0), NCELL-1);
          int idx = (int)lutg[dim*NCELL + c];
          float v = sp[idx];
          while (v < x) { ++idx; v = sp[idx]; }
          float dn = v - x;
          float dpv = (idx > 0) ? (x - sp[idx-1]) : 3.0e38f;
          md1[d] = fminf(dn, dpv);
        }
      }
      *(float2*)&tokbuf[(2*rp)*TBSTR + dp*2]   = make_float2(md0[0]*md0[0]*msk0, md0[1]*md0[1]*msk0);
      *(float2*)&tokbuf[(2*rp+1)*TBSTR + dp*2] = make_float2(md1[0]*md1[0]*msk1, md1[1]*md1[1]*msk1);
    }
    lds_fence();

    // --- hit detection + message update (DPP 8-lane sums, top-lane ballot) ---
    {
      float tokr[8][4];
      #pragma unroll
      for (int rr = 0; rr < 8; ++rr) ld4(tokr[rr], &tokbuf[(w*8+rr)*TBSTR + d0u]);
      const bool top = ((c4 & 7) == 7);   // only top lane of each 8-lane tg group has clean sums
      unsigned newfin = fin;
      #pragma unroll
      for (int rr = 0; rr < 8; ++rr) {
        float pd = 0.f, ed = 0.f;
        #pragma unroll
        for (int k = 0; k < 4; ++k) { float dm = tokr[rr][k]-MSGr[rr][k]; pd += dm*dm; }
        if (tg == 0) {
          #pragma unroll
          for (int k = 0; k < 4; ++k) { float de = tokr[rr][k]-eosv[k]; ed += de*de; }
        }
        pd = grp8_sum(pd);   // valid at top lanes only
        ed = grp8_sum(ed);
        bool lane_hit = top && ((tg < it && pd < EPSI) || (tg == 0 && ed < EPSI));
        bool hit = (__ballot(lane_hit) != 0ull);
        if (hit) {
          if ((tg == it) && !((fin >> rr) & 1u)) {
            #pragma unroll
            for (int k = 0; k < 4; ++k) tokr[rr][k] = eosv[k];
          }
          newfin |= (1u << rr);
        }
        if (tg == it) {
          #pragma unroll
          for (int k = 0; k < 4; ++k) MSGr[rr][k] = tokr[rr][k];
        }
      }
      if (tg == it) {
        #pragma unroll
        for (int rr = 0; rr < 8; ++rr)
          *(float4*)&tokbuf[(w*8+rr)*TBSTR + d0u] =
              make_float4(MSGr[rr][0], MSGr[rr][1], MSGr[rr][2], MSGr[rr][3]);
      }
      fin = newfin;
    }
    lds_fence();
  }

  // ---------------- final: comm sum + two block-coop GEMVs + relu ----------------
  __syncthreads();                 // all waves done with ha before aliasing
  float* commb = ha;               // [4][HAS] rows 0..3
  float* o1    = ha + 4*HAS;       // [4][HAS] rows 4..7
  {
    float cs[4] = {0,0,0,0};
    #pragma unroll
    for (int rr = 0; rr < 8; ++rr) {
      #pragma unroll
      for (int k = 0; k < 4; ++k) cs[k] += MSGr[rr][k];
    }
    const float i7 = 1.0f/7.0f;
    *(float4*)&commb[w*HAS + c4*4] = make_float4(cs[0]*i7, cs[1]*i7, cs[2]*i7, cs[3]*i7);
  }
  __syncthreads();
  {
    float bs = bsum[t];
    float a1[4] = {bs, bs, bs, bs};
    #pragma unroll 2
    for (int jq = 0; jq < 64; ++jq) {
      float w4[4];
      #pragma unroll
      for (int m = 0; m < 4; ++m) w4[m] = Wsum[(size_t)(jq*4+m)*HIDN + t];
      #pragma unroll
      for (int g = 0; g < 4; ++g) {
        float c[4]; ld4(c, &commb[g*HAS + jq*4]);   // uniform broadcast
        a1[g] += c[0]*w4[0] + c[1]*w4[1] + c[2]*w4[2] + c[3]*w4[3];
      }
    }
    #pragma unroll
    for (int g = 0; g < 4; ++g) o1[g*HAS + t] = a1[g];
  }
  __syncthreads();
  {
    float bh = bhead[t];
    float a2[4] = {bh, bh, bh, bh};
    #pragma unroll 2
    for (int jq = 0; jq < 64; ++jq) {
      float w4[4];
      #pragma unroll
      for (int m = 0; m < 4; ++m) w4[m] = Whead[(size_t)(jq*4+m)*HIDN + t];
      #pragma unroll
      for (int g = 0; g < 4; ++g) {
        float c[4]; ld4(c, &o1[g*HAS + jq*4]);
        a2[g] += c[0]*w4[0] + c[1]*w4[1] + c[2]*w4[2] + c[3]*w4[3];
      }
    }
    #pragma unroll
    for (int g = 0; g < 4; ++g) {
      float r = fmaxf(a2[g], 0.f);
      #pragma unroll
      for (int rr = 0; rr < 8; ++rr)
        out[(size_t)(rowbase + g*8 + rr)*HIDN + t] = r;
    }
  }
}

extern "C" void kernel_launch(void* const* d_in, const int* in_sizes, int n_in,
                              void* d_out, int out_size, void* d_ws, size_t ws_size,
                              hipStream_t stream) {
    const float* hs    = (const float*)d_in[0];
    const float* eps   = (const float*)d_in[1];
    const float* WQ    = (const float*)d_in[2];
    const float* bQ    = (const float*)d_in[3];
    const float* WK    = (const float*)d_in[4];
    const float* bK    = (const float*)d_in[5];
    const float* Wmu   = (const float*)d_in[6];
    const float* bmu   = (const float*)d_in[7];
    const float* Wvar  = (const float*)d_in[8];
    const float* bvar  = (const float*)d_in[9];
    const float* vocab = (const float*)d_in[10];
    const float* Wsum  = (const float*)d_in[11];
    const float* bsum  = (const float*)d_in[12];
    const float* Whead = (const float*)d_in[13];
    const float* bhead = (const float*)d_in[14];
    float* o = (float*)d_out;
    float* wsf = (float*)d_ws;
    int Btot = in_sizes[0] / HIDN;
    hipLaunchKernelGGL(sort_vocab, dim3(32), dim3(256), 0, stream, vocab, Wmu, Wvar, wsf);
    hipLaunchKernelGGL(mac_fused, dim3(Btot / ROWSB), dim3(256), 0, stream,
                       hs, eps, WQ, bQ, WK, bK, Wmu, bmu, Wvar, bvar,
                       vocab, Wsum, bsum, Whead, bhead, wsf, o, Btot);
}

// Round 14
// 346.563 us; speedup vs baseline: 1.0377x; 1.0190x over previous
//
#include <hip/hip_runtime.h>

#define ROWSB 32     // rows per block; 4 waves x 8 rows (wave == agent group)
#define HIDN 256
#define TT 8
#define EPSI 1e-6f
#define HAS 260      // ha/vbuf row stride (floats)
#define SVS 260      // sorted-vocab row stride in ws (257 used + 3 INF pad)
#define TBSTR 40
#define NCELL 512
#define WS_LUT_F   (32*SVS)                 // ushort lut[32][512] == 8192 floats
#define WS_DINFO_F (32*SVS + 8192)          // float2 dinfo[32] (base, scale)
#define WS_WMV_F   (32*SVS + 8192 + 64)     // interleaved [j][d][(mu,var)] = 16384 floats

__device__ __forceinline__ void ld4(float* d, const float* p) {
  float4 v = *(const float4*)p;
  d[0] = v.x; d[1] = v.y; d[2] = v.z; d[3] = v.w;
}
__device__ __forceinline__ void ld2(float* d, const float* p) {
  float2 v = *(const float2*)p;
  d[0] = v.x; d[1] = v.y;
}
// Order own-wave LDS write->read without draining the global-load (vmcnt) queue.
__device__ __forceinline__ void lds_fence() {
  asm volatile("s_waitcnt lgkmcnt(0)" ::: "memory");
}
// 8 FMAs for one j: wv = (mu[d0],var[d0],mu[d1],var[d1]); h0/h1 = ha[row0/1][j]
__device__ __forceinline__ void fma8(float4 wv, float h0, float h1,
                                     float* mu0, float* lv0, float* mu1, float* lv1) {
  mu0[0] += h0*wv.x; lv0[0] += h0*wv.y; mu0[1] += h0*wv.z; lv0[1] += h0*wv.w;
  mu1[0] += h1*wv.x; lv1[0] += h1*wv.y; mu1[1] += h1*wv.z; lv1[1] += h1*wv.w;
}

// ---- DPP cross-lane reductions (pure VALU, zero lgkm) ----
#define DPP_ADD(x, ctrl) \
  (x) += __int_as_float(__builtin_amdgcn_update_dpp(0, __float_as_int(x), (ctrl), 0xf, 0xf, true))
__device__ __forceinline__ float wave_sum64(float x) {
  DPP_ADD(x, 0x111);  // row_shr:1
  DPP_ADD(x, 0x112);  // row_shr:2
  DPP_ADD(x, 0x114);  // row_shr:4
  DPP_ADD(x, 0x118);  // row_shr:8
  DPP_ADD(x, 0x142);  // row_bcast:15
  DPP_ADD(x, 0x143);  // row_bcast:31 -> lane63 = sum(0..63)
  return __int_as_float(__builtin_amdgcn_readlane(__float_as_int(x), 63));
}
// 8-lane group sum: valid ONLY at top lane of each group (c4 & 7) == 7.
__device__ __forceinline__ float grp8_sum(float x) {
  DPP_ADD(x, 0x111);
  DPP_ADD(x, 0x112);
  DPP_ADD(x, 0x114);
  return x;
}

// ---------- pre-pass: per-dim bitonic sort + 512-cell LUT + (mu,var) weight interleave ----------
__global__ __launch_bounds__(256)
void sort_vocab(const float* __restrict__ vocab,
                const float* __restrict__ Wmu, const float* __restrict__ Wvar,
                float* __restrict__ ws) {
  __shared__ float arr[512];
  const int d = blockIdx.x;
  const int t = threadIdx.x;
  ws[WS_WMV_F + ((size_t)t*32 + d)*2 + 0] = Wmu[(size_t)t*32 + d];
  ws[WS_WMV_F + ((size_t)t*32 + d)*2 + 1] = Wvar[(size_t)t*32 + d];
  arr[t] = (t < 257) ? vocab[t*32 + d] : 3.0e38f;
  arr[t+256] = (t == 0) ? vocab[256*32 + d] : 3.0e38f;
  __syncthreads();
  for (int k = 2; k <= 512; k <<= 1) {
    for (int j = k >> 1; j > 0; j >>= 1) {
      #pragma unroll
      for (int h = 0; h < 2; ++h) {
        int i = t + h*256;
        int ixj = i ^ j;
        if (ixj > i) {
          float a = arr[i], b = arr[ixj];
          bool up = ((i & k) == 0);
          if ((a > b) == up) { arr[i] = b; arr[ixj] = a; }
        }
      }
      __syncthreads();
    }
  }
  #pragma unroll
  for (int h = 0; h < 2; ++h) {
    int i = t + h*256;
    if (i < SVS) ws[d*SVS + i] = (i < 257) ? arr[i] : 3.0e38f;
  }
  float base = arr[0];
  float maxv = arr[256];
  float scale = (float)NCELL / fmaxf(maxv - base, 1e-30f);
  if (t == 0) {
    float2* dinfo = (float2*)(ws + WS_DINFO_F);
    dinfo[d] = make_float2(base, scale);
  }
  #pragma unroll
  for (int h = 0; h < 2; ++h) {
    int cell = t + h*256;
    float target = base + (float)cell * (maxv - base) * (1.0f/(float)NCELL);
    int lo = 0, hi = 257;
    while (lo < hi) { int mid = (lo+hi)>>1; if (arr[mid] < target) lo = mid+1; else hi = mid; }
    ((unsigned short*)(ws + WS_LUT_F))[d*NCELL + cell] = (unsigned short)lo;
  }
}

// ---------- main fused kernel: 8 rows/wave, DPP reductions, zero-cost latency edits ----------
// FINAL (r14 == r13, 280us steady-state). Structural ceiling, measured across r0-r13:
//  * occupancy pinned at 2 waves/SIMD three ways: work decomposition (8 rows/wave =
//    2048 waves; 4 rows/wave costs +26% instr and still lands 2 blocks/CU -- r9),
//    LDS (72KB), and the unified-reg-file law (launch_bounds N=1 -> AGPR parking ->
//    1 wave/SIMD -- r5/r6). N=2 + demand<=128 is the unique clean point (r7).
//  * latency-bound, not issue-bound: pk_fma halved FMA issue, VALUBusy 58->48.5%,
//    dur FLAT (r11). Deeper prefetch spills hot at the 128-reg cap (r12).
//  * fp32 mandatory: bf16 state perturbs the 1e-6-threshold hit compare -> 0.096
//    output error (r3). No fp32 MFMA on CDNA4 -> VALU floor ~37k FMA/wave.
//  * 100%-busy bound ~168us; achieved 280us @ 60% busy; the 40% stall is the
//    serialized per-iteration phase chain at 2 waves/SIMD of TLP.
__global__ __launch_bounds__(256, 2)
void mac_fused(const float* __restrict__ hs, const float* __restrict__ eps,
               const float* __restrict__ WQ, const float* __restrict__ bQ,
               const float* __restrict__ WK, const float* __restrict__ bK,
               const float* __restrict__ Wmu, const float* __restrict__ bmu,
               const float* __restrict__ Wvar, const float* __restrict__ bvar,
               const float* __restrict__ vocab,
               const float* __restrict__ Wsum, const float* __restrict__ bsum,
               const float* __restrict__ Whead, const float* __restrict__ bhead,
               const float* __restrict__ ws, float* __restrict__ out, int Btot)
{
  // 71,680 B LDS -> 2 blocks/CU
  __shared__ __align__(16) float ha[ROWSB*HAS];       // wave-private rows; end: comm/o1 alias
  __shared__ __align__(16) float vbuf[ROWSB*HAS];     // V, wave-private, written once
  __shared__ __align__(16) float tokbuf[ROWSB*TBSTR]; // wave-private rows

  const int t   = threadIdx.x;
  const int c4  = t & 63;
  const int w   = t >> 6;         // wave id; rows w*8..w*8+7 (one agent group)
  const int rp  = t >> 4;         // sampling row-pair: block rows 2rp, 2rp+1 (in own octet)
  const int lp  = (t >> 4) & 3;   // local row-pair within wave: local rows 2lp, 2lp+1
  const int dp  = t & 15;         // sampling dim-pair: dims 2dp, 2dp+1
  const int d0u = (c4 << 2) & 31;
  const int tg  = c4 >> 3;        // token slot of this thread's cols
  const int rowbase = blockIdx.x * ROWSB;

  float Qr[8][4], Kr[8][4], MSGr[8][4];
  float eosv[4];
  unsigned fin = 0u;

  // ---------------- staging (all wave-private) ----------------
  {
    const float* hp = hs + (size_t)(rowbase + w*8)*HIDN + c4*4;
    #pragma unroll
    for (int rr = 0; rr < 8; ++rr)
      *(float4*)&ha[(w*8+rr)*HAS + c4*4] = *(const float4*)(hp + (size_t)rr*HIDN);
  }
  ld4(eosv, vocab + 256*32 + d0u);
  float dbr[2], dsr[2];
  {
    float t0[4];
    ld4(t0, ws + WS_DINFO_F + dp*4);   // dinfo[2dp], dinfo[2dp+1]
    dbr[0]=t0[0]; dsr[0]=t0[1]; dbr[1]=t0[2]; dsr[1]=t0[3];
  }
  float bm[2], bv[2];
  ld2(bm, bmu + dp*2); ld2(bv, bvar + dp*2);
  lds_fence();   // own-wave ha writes ordered before cross-lane reads

  // ------------- initial GEMM: Q = hs@WQ + bQ ; V = hs@WK + bK (V -> vbuf) -------------
  {
    float Vr[8][4];
    {
      float bq[4], bk[4];
      ld4(bq, bQ + c4*4); ld4(bk, bK + c4*4);
      #pragma unroll
      for (int rr = 0; rr < 8; ++rr) {
        #pragma unroll
        for (int k = 0; k < 4; ++k) { Qr[rr][k] = bq[k]; Vr[rr][k] = bk[k]; }
      }
    }
    #pragma unroll 2
    for (int jq = 0; jq < 64; ++jq) {
      float hsq[8][4];
      #pragma unroll
      for (int rr = 0; rr < 8; ++rr) ld4(hsq[rr], &ha[(w*8+rr)*HAS + jq*4]);
      #pragma unroll
      for (int m = 0; m < 4; ++m) {
        float wq[4], wk[4];
        ld4(wq, WQ + (size_t)(jq*4+m)*HIDN + c4*4);
        ld4(wk, WK + (size_t)(jq*4+m)*HIDN + c4*4);
        #pragma unroll
        for (int rr = 0; rr < 8; ++rr) {
          #pragma unroll
          for (int k = 0; k < 4; ++k) {
            Qr[rr][k] += hsq[rr][m]*wq[k];
            Vr[rr][k] += hsq[rr][m]*wk[k];
          }
        }
      }
    }
    // park V in LDS (same lane writes and later reads these addresses)
    #pragma unroll
    for (int rr = 0; rr < 8; ++rr)
      *(float4*)&vbuf[(w*8+rr)*HAS + c4*4] =
          make_float4(Vr[rr][0], Vr[rr][1], Vr[rr][2], Vr[rr][3]);
  }
  {
    float bk[4]; ld4(bk, bK + c4*4);
    #pragma unroll
    for (int rr = 0; rr < 8; ++rr) {
      #pragma unroll
      for (int k = 0; k < 4; ++k) {
        Qr[rr][k] *= (1.0f/256.0f);   // bake NF^2: logit = -(Qr*Kr)
        Kr[rr][k]   = bk[k];
        MSGr[rr][k] = 0.f;
      }
    }
  }
  lds_fence();

  // ---------------- token recurrence (wave-private; zero block barriers) ----------------
  for (int it = 0; it < TT; ++it) {
    if (it > 0) {
      const float* Wr = WK + (size_t)((it-1)*32)*HIDN + c4*4;
      __builtin_amdgcn_s_setprio(1);
      #pragma unroll 2
      for (int cq = 0; cq < 8; ++cq) {
        float tq[8][4];
        #pragma unroll
        for (int rr = 0; rr < 8; ++rr) ld4(tq[rr], &tokbuf[(w*8+rr)*TBSTR + cq*4]);
        #pragma unroll
        for (int m = 0; m < 4; ++m) {
          float wv[4]; ld4(wv, Wr + (size_t)(cq*4+m)*HIDN);
          #pragma unroll
          for (int rr = 0; rr < 8; ++rr) {
            #pragma unroll
            for (int k = 0; k < 4; ++k) Kr[rr][k] += tq[rr][m]*wv[k];
          }
        }
      }
      __builtin_amdgcn_s_setprio(0);
    }

    // eps prefetch for both sampling rows
    float ep0[2], ep1[2];
    ld2(ep0, eps + ((size_t)it*Btot + rowbase + 2*rp)*32 + dp*2);
    ld2(ep1, eps + ((size_t)it*Btot + rowbase + 2*rp+1)*32 + dp*2);

    // --- softmax(-(Q*K)) without max-sub (|logit|<~2e-3); store e*V; capture 1/s in regs ---
    float iv0 = 0.f, iv1 = 0.f;
    #pragma unroll
    for (int rr = 0; rr < 8; ++rr) {
      float e[4]; float p = 0.f;
      #pragma unroll
      for (int k = 0; k < 4; ++k) { e[k] = __expf(-(Qr[rr][k]*Kr[rr][k])); p += e[k]; }
      float s = wave_sum64(p);           // uniform across the wave
      if (rr == 2*lp)     iv0 = 1.0f / s;
      if (rr == 2*lp + 1) iv1 = 1.0f / s;
      float vv[4];
      ld4(vv, &vbuf[(w*8+rr)*HAS + c4*4]);   // own-lane V readback
      *(float4*)&ha[(w*8+rr)*HAS + c4*4] =
          make_float4(e[0]*vv[0], e[1]*vv[1], e[2]*vv[2], e[3]*vv[3]);
    }
    lds_fence();

    // --- GEMV (2 rows x 2 dims/thread; 4-j double-buffered weight stream, 32 regs) ---
    float mu0[2]={0,0}, lv0[2]={0,0}, mu1[2]={0,0}, lv1[2]={0,0};
    {
      const float* wmv  = ws + WS_WMV_F + dp*4;   // + j*64 per weight row j
      const float* har0 = &ha[(2*rp)*HAS];
      const float* har1 = &ha[(2*rp+1)*HAS];
      float4 wb0[4], wb1[4];
      #pragma unroll
      for (int u = 0; u < 4; ++u) wb0[u] = *(const float4*)(wmv + (size_t)u*64);
      __builtin_amdgcn_s_setprio(1);
      #pragma unroll 1
      for (int bb = 0; bb < 32; ++bb) {
        {   // window b = 2bb (j = 4b..4b+3, weights in wb0); prefetch b+1 into wb1
          const int b = 2*bb;
          float4 h0 = *(const float4*)(har0 + b*4);
          float4 h1 = *(const float4*)(har1 + b*4);
          const float* wp = wmv + (size_t)(b+1)*256;
          #pragma unroll
          for (int u = 0; u < 4; ++u) wb1[u] = *(const float4*)(wp + (size_t)u*64);
          fma8(wb0[0], h0.x, h1.x, mu0, lv0, mu1, lv1);
          fma8(wb0[1], h0.y, h1.y, mu0, lv0, mu1, lv1);
          fma8(wb0[2], h0.z, h1.z, mu0, lv0, mu1, lv1);
          fma8(wb0[3], h0.w, h1.w, mu0, lv0, mu1, lv1);
        }
        {   // window b = 2bb+1 (weights in wb1); prefetch b+1 into wb0
          const int b = 2*bb+1;
          float4 h0 = *(const float4*)(har0 + b*4);
          float4 h1 = *(const float4*)(har1 + b*4);
          if (bb < 31) {
            const float* wp = wmv + (size_t)(b+1)*256;
            #pragma unroll
            for (int u = 0; u < 4; ++u) wb0[u] = *(const float4*)(wp + (size_t)u*64);
          }
          fma8(wb1[0], h0.x, h1.x, mu0, lv0, mu1, lv1);
          fma8(wb1[1], h0.y, h1.y, mu0, lv0, mu1, lv1);
          fma8(wb1[2], h0.z, h1.z, mu0, lv0, mu1, lv1);
          fma8(wb1[3], h0.w, h1.w, mu0, lv0, mu1, lv1);
        }
      }
      __builtin_amdgcn_s_setprio(0);
    }
    // --- sample + quantize via sorted scan (global, L2-hot, NCELL=512) ---
    {
      float msk0 = ((fin >> (2*lp))   & 1u) ? 0.f : 1.f;
      float msk1 = ((fin >> (2*lp+1)) & 1u) ? 0.f : 1.f;
      const unsigned short* lutg = (const unsigned short*)(ws + WS_LUT_F);
      float md0[2], md1[2];
      #pragma unroll
      for (int d = 0; d < 2; ++d) {
        const int dim = 2*dp + d;
        const float* sp = ws + dim*SVS;
        {
          float mu = mu0[d]*iv0 + bm[d];
          float lv = lv0[d]*iv0 + bv[d];
          float x  = ep0[d]*__expf(0.5f*lv) + mu;
          int c = (int)((x - dbr[d]) * dsr[d]);
          c = min(max(c, 0), NCELL-1);
          int idx = (int)lutg[dim*NCELL + c];
          float v = sp[idx];
          while (v < x) { ++idx; v = sp[idx]; }   // pads +INF -> terminates
          float dn = v - x;
          float dpv = (idx > 0) ? (x - sp[idx-1]) : 3.0e38f;
          md0[d] = fminf(dn, dpv);
        }
        {
          float mu = mu1[d]*iv1 + bm[d];
          float lv = lv1[d]*iv1 + bv[d];
          float x  = ep1[d]*__expf(0.5f*lv) + mu;
          int c = (int)((x - dbr[d]) * dsr[d]);
          c = min(max(c, 0), NCELL-1);
          int idx = (int)lutg[dim*NCELL + c];
          float v = sp[idx];
          while (v < x) { ++idx; v = sp[idx]; }
          float dn = v - x;
          float dpv = (idx > 0) ? (x - sp[idx-1]) : 3.0e38f;
          md1[d] = fminf(dn, dpv);
        }
      }
      *(float2*)&tokbuf[(2*rp)*TBSTR + dp*2]   = make_float2(md0[0]*md0[0]*msk0, md0[1]*md0[1]*msk0);
      *(float2*)&tokbuf[(2*rp+1)*TBSTR + dp*2] = make_float2(md1[0]*md1[0]*msk1, md1[1]*md1[1]*msk1);
    }
    lds_fence();

    // --- hit detection + message update (DPP 8-lane sums, top-lane ballot) ---
    {
      float tokr[8][4];
      #pragma unroll
      for (int rr = 0; rr < 8; ++rr) ld4(tokr[rr], &tokbuf[(w*8+rr)*TBSTR + d0u]);
      const bool top = ((c4 & 7) == 7);   // only top lane of each 8-lane tg group has clean sums
      unsigned newfin = fin;
      #pragma unroll
      for (int rr = 0; rr < 8; ++rr) {
        float pd = 0.f, ed = 0.f;
        #pragma unroll
        for (int k = 0; k < 4; ++k) { float dm = tokr[rr][k]-MSGr[rr][k]; pd += dm*dm; }
        if (tg == 0) {
          #pragma unroll
          for (int k = 0; k < 4; ++k) { float de = tokr[rr][k]-eosv[k]; ed += de*de; }
        }
        pd = grp8_sum(pd);   // valid at top lanes only
        ed = grp8_sum(ed);
        bool lane_hit = top && ((tg < it && pd < EPSI) || (tg == 0 && ed < EPSI));
        bool hit = (__ballot(lane_hit) != 0ull);
        if (hit) {
          if ((tg == it) && !((fin >> rr) & 1u)) {
            #pragma unroll
            for (int k = 0; k < 4; ++k) tokr[rr][k] = eosv[k];
          }
          newfin |= (1u << rr);
        }
        if (tg == it) {
          #pragma unroll
          for (int k = 0; k < 4; ++k) MSGr[rr][k] = tokr[rr][k];
        }
      }
      if (tg == it) {
        #pragma unroll
        for (int rr = 0; rr < 8; ++rr)
          *(float4*)&tokbuf[(w*8+rr)*TBSTR + d0u] =
              make_float4(MSGr[rr][0], MSGr[rr][1], MSGr[rr][2], MSGr[rr][3]);
      }
      fin = newfin;
    }
    lds_fence();
  }

  // ---------------- final: comm sum + two block-coop GEMVs + relu ----------------
  __syncthreads();                 // all waves done with ha before aliasing
  float* commb = ha;               // [4][HAS] rows 0..3
  float* o1    = ha + 4*HAS;       // [4][HAS] rows 4..7
  {
    float cs[4] = {0,0,0,0};
    #pragma unroll
    for (int rr = 0; rr < 8; ++rr) {
      #pragma unroll
      for (int k = 0; k < 4; ++k) cs[k] += MSGr[rr][k];
    }
    const float i7 = 1.0f/7.0f;
    *(float4*)&commb[w*HAS + c4*4] = make_float4(cs[0]*i7, cs[1]*i7, cs[2]*i7, cs[3]*i7);
  }
  __syncthreads();
  {
    float bs = bsum[t];
    float a1[4] = {bs, bs, bs, bs};
    #pragma unroll 2
    for (int jq = 0; jq < 64; ++jq) {
      float w4[4];
      #pragma unroll
      for (int m = 0; m < 4; ++m) w4[m] = Wsum[(size_t)(jq*4+m)*HIDN + t];
      #pragma unroll
      for (int g = 0; g < 4; ++g) {
        float c[4]; ld4(c, &commb[g*HAS + jq*4]);   // uniform broadcast
        a1[g] += c[0]*w4[0] + c[1]*w4[1] + c[2]*w4[2] + c[3]*w4[3];
      }
    }
    #pragma unroll
    for (int g = 0; g < 4; ++g) o1[g*HAS + t] = a1[g];
  }
  __syncthreads();
  {
    float bh = bhead[t];
    float a2[4] = {bh, bh, bh, bh};
    #pragma unroll 2
    for (int jq = 0; jq < 64; ++jq) {
      float w4[4];
      #pragma unroll
      for (int m = 0; m < 4; ++m) w4[m] = Whead[(size_t)(jq*4+m)*HIDN + t];
      #pragma unroll
      for (int g = 0; g < 4; ++g) {
        float c[4]; ld4(c, &o1[g*HAS + jq*4]);
        a2[g] += c[0]*w4[0] + c[1]*w4[1] + c[2]*w4[2] + c[3]*w4[3];
      }
    }
    #pragma unroll
    for (int g = 0; g < 4; ++g) {
      float r = fmaxf(a2[g], 0.f);
      #pragma unroll
      for (int rr = 0; rr < 8; ++rr)
        out[(size_t)(rowbase + g*8 + rr)*HIDN + t] = r;
    }
  }
}

extern "C" void kernel_launch(void* const* d_in, const int* in_sizes, int n_in,
                              void* d_out, int out_size, void* d_ws, size_t ws_size,
                              hipStream_t stream) {
    const float* hs    = (const float*)d_in[0];
    const float* eps   = (const float*)d_in[1];
    const float* WQ    = (const float*)d_in[2];
    const float* bQ    = (const float*)d_in[3];
    const float* WK    = (const float*)d_in[4];
    const float* bK    = (const float*)d_in[5];
    const float* Wmu   = (const float*)d_in[6];
    const float* bmu   = (const float*)d_in[7];
    const float* Wvar  = (const float*)d_in[8];
    const float* bvar  = (const float*)d_in[9];
    const float* vocab = (const float*)d_in[10];
    const float* Wsum  = (const float*)d_in[11];
    const float* bsum  = (const float*)d_in[12];
    const float* Whead = (const float*)d_in[13];
    const float* bhead = (const float*)d_in[14];
    float* o = (float*)d_out;
    float* wsf = (float*)d_ws;
    int Btot = in_sizes[0] / HIDN;
    hipLaunchKernelGGL(sort_vocab, dim3(32), dim3(256), 0, stream, vocab, Wmu, Wvar, wsf);
    hipLaunchKernelGGL(mac_fused, dim3(Btot / ROWSB), dim3(256), 0, stream,
                       hs, eps, WQ, bQ, WK, bK, Wmu, bmu, Wvar, bvar,
                       vocab, Wsum, bsum, Whead, bhead, wsf, o, Btot);
}